// Round 1
// baseline (714.610 us; speedup 1.0000x reference)
//
#include <hip/hip_runtime.h>
#include <math.h>

#define NB 2
#define NROWS (NB * 20)
#define NTHR 256

__device__ __forceinline__ float relu_f(float v) { return fmaxf(v, 0.f); }

// Dense layer over LDS activations, rows = NROWS.
// Thread owns W output columns x R rows; weights loaded once per 16 FMAs.
template <int K, int C, int W, int R, bool RELU, bool GPART>
__device__ void dense_layer(const float* __restrict__ Wt, const float* __restrict__ bias,
                            const float* xin, int s_in, float* xout, int s_out,
                            const float* gpart, int tid) {
  constexpr int JP = C / W;
  constexpr int NG = NROWS / R;
  constexpr int ITEMS = JP * NG;
  for (int it = tid; it < ITEMS; it += NTHR) {
    const int jg = it % JP;
    const int g = it / JP;
    const int j = jg * W;
    const int n0 = g * R;
    float acc[R][W];
#pragma unroll
    for (int r = 0; r < R; ++r) {
#pragma unroll
      for (int w = 0; w < W; ++w) {
        float a = bias[j + w];
        if constexpr (GPART) a += gpart[((n0 + r) / 20) * 104 + j + w];
        acc[r][w] = a;
      }
    }
    int k0 = 0;
    for (; k0 + 4 <= K; k0 += 4) {
      float4 xr[R];
#pragma unroll
      for (int r = 0; r < R; ++r)
        xr[r] = *reinterpret_cast<const float4*>(&xin[(n0 + r) * s_in + k0]);
      float wv[4][W];
#pragma unroll
      for (int kk = 0; kk < 4; ++kk) {
        if constexpr (W == 2) {
          float2 w2 = *reinterpret_cast<const float2*>(&Wt[(k0 + kk) * C + j]);
          wv[kk][0] = w2.x; wv[kk][1] = w2.y;
        } else {
#pragma unroll
          for (int w = 0; w < W; ++w) wv[kk][w] = Wt[(k0 + kk) * C + j + w];
        }
      }
#pragma unroll
      for (int r = 0; r < R; ++r) {
#pragma unroll
        for (int w = 0; w < W; ++w) {
          acc[r][w] += xr[r].x * wv[0][w];
          acc[r][w] += xr[r].y * wv[1][w];
          acc[r][w] += xr[r].z * wv[2][w];
          acc[r][w] += xr[r].w * wv[3][w];
        }
      }
    }
    for (; k0 < K; ++k0) {
      float xs_[R];
#pragma unroll
      for (int r = 0; r < R; ++r) xs_[r] = xin[(n0 + r) * s_in + k0];
#pragma unroll
      for (int w = 0; w < W; ++w) {
        float wv = Wt[k0 * C + j + w];
#pragma unroll
        for (int r = 0; r < R; ++r) acc[r][w] += xs_[r] * wv;
      }
    }
#pragma unroll
    for (int r = 0; r < R; ++r) {
#pragma unroll
      for (int w = 0; w < W; ++w) {
        float v = acc[r][w];
        if constexpr (RELU) v = relu_f(v);
        xout[(n0 + r) * s_out + j + w] = v;
      }
    }
  }
}

// Single-row dot against column j of a KxC weight matrix; xin is LDS (broadcast).
template <int K>
__device__ __forceinline__ float mrow_dot(const float* __restrict__ Wt, int C, int j,
                                          const float* xin) {
  float acc = 0.f;
  int k0 = 0;
  for (; k0 + 4 <= K; k0 += 4) {
    float4 xv = *reinterpret_cast<const float4*>(&xin[k0]);
    acc += xv.x * Wt[(k0 + 0) * C + j];
    acc += xv.y * Wt[(k0 + 1) * C + j];
    acc += xv.z * Wt[(k0 + 2) * C + j];
    acc += xv.w * Wt[(k0 + 3) * C + j];
  }
  for (; k0 < K; ++k0) acc += xin[k0] * Wt[k0 * C + j];
  return acc;
}

__global__ __launch_bounds__(NTHR) void value_net_kernel(
    const float* __restrict__ state,
    const float* __restrict__ w1, const float* __restrict__ b1,
    const float* __restrict__ w2, const float* __restrict__ b2,
    const float* __restrict__ w3, const float* __restrict__ b3,
    const float* __restrict__ a1, const float* __restrict__ ab1,
    const float* __restrict__ a2, const float* __restrict__ ab2,
    const float* __restrict__ a3, const float* __restrict__ ab3,
    const float* __restrict__ m1, const float* __restrict__ mb1,
    const float* __restrict__ m2, const float* __restrict__ mb2,
    const float* __restrict__ m3, const float* __restrict__ mb3,
    const float* __restrict__ m4, const float* __restrict__ mb4,
    float* __restrict__ out) {
  __shared__ float xs[NROWS * 16];      // state rows, stride 16 (13 used)
  __shared__ float h1[NROWS * 152];     // 13->150 out; later reused as s1 (stride 104)
  __shared__ float h2[NROWS * 104];     // 150->100 out; later reused as s2
  __shared__ float feat[NROWS * 104];   // mlp1_out
  __shared__ float gs[NB * 104];        // mean over n
  __shared__ float gpart[NB * 104];     // gs @ a1[100:200] (no bias)
  __shared__ float sce[NB * 32];        // relu'd scores
  __shared__ float sw[NB * 32];         // softmax weights
  __shared__ float wf[NB * 104];        // weighted feature
  __shared__ float joint[NB * 112];     // [self(6), wf(100)]
  __shared__ float v1[NB * 152];
  __shared__ float v2[NB * 104];
  __shared__ float v3[NB * 104];
  __shared__ float psum[NB * 100];

  const int tid = threadIdx.x;
  const int b0 = blockIdx.x * NB;
  float* s1 = h1;  // stride 104
  float* s2 = h2;  // stride 104

  // P0: stage state rows into LDS
  for (int i = tid; i < NB * 260; i += NTHR) {
    int bl = i / 260;
    int rem = i - bl * 260;
    int n = rem / 13;
    int k = rem - n * 13;
    xs[(bl * 20 + n) * 16 + k] = state[(b0 + bl) * 260 + rem];
  }
  __syncthreads();

  // P1: L1 13->150 relu
  dense_layer<13, 150, 2, 8, true, false>(w1, b1, xs, 16, h1, 152, nullptr, tid);
  __syncthreads();
  // P2: L2 150->100 relu
  dense_layer<150, 100, 2, 8, true, false>(w2, b2, h1, 152, h2, 104, nullptr, tid);
  __syncthreads();
  // P3: L3 100->100 (no relu) -> feat
  dense_layer<100, 100, 2, 8, false, false>(w3, b3, h2, 104, feat, 104, nullptr, tid);
  __syncthreads();

  // P4: gs = mean over n
  if (tid < NB * 100) {
    int b = tid / 100, d = tid - b * 100;
    float s = 0.f;
    for (int n = 0; n < 20; ++n) s += feat[(b * 20 + n) * 104 + d];
    gs[b * 104 + d] = s * 0.05f;
  }
  __syncthreads();

  // P4b: gpart = gs @ a1[100:200]  (bias added inside A1)
  if (tid < NB * 100) {
    int b = tid / 100, j = tid - b * 100;
    float acc = 0.f;
    for (int k = 0; k < 100; ++k) acc += gs[b * 104 + k] * a1[(100 + k) * 100 + j];
    gpart[b * 104 + j] = acc;
  }
  __syncthreads();

  // P5: A1 (feat part, K=100) + gpart + ab1, relu -> s1
  dense_layer<100, 100, 2, 8, true, true>(a1, ab1, feat, 104, s1, 104, gpart, tid);
  __syncthreads();
  // P6: A2 100->100 relu -> s2
  dense_layer<100, 100, 2, 8, true, false>(a2, ab2, s1, 104, s2, 104, nullptr, tid);
  __syncthreads();

  // P7: A3 100->1, relu -> scores
  if (tid < NROWS) {
    int b = tid / 20, n = tid - b * 20;
    float acc = ab3[0] + mrow_dot<100>(a3, 1, 0, &s2[tid * 104]);
    sce[b * 32 + n] = relu_f(acc);
  }
  __syncthreads();

  // P7b: softmax over n (each row-thread redundantly computes max/sum)
  if (tid < NROWS) {
    int b = tid / 20, n = tid - b * 20;
    float m = -1e30f;
    for (int i = 0; i < 20; ++i) m = fmaxf(m, sce[b * 32 + i]);
    float sum = 0.f, mine = 0.f;
    for (int i = 0; i < 20; ++i) {
      float e = __expf(sce[b * 32 + i] - m);
      sum += e;
      if (i == n) mine = e;
    }
    sw[b * 32 + n] = mine / sum;
  }
  __syncthreads();

  // P8: weighted feature
  if (tid < NB * 100) {
    int b = tid / 100, d = tid - b * 100;
    float acc = 0.f;
    for (int n = 0; n < 20; ++n) acc += sw[b * 32 + n] * feat[(b * 20 + n) * 104 + d];
    wf[b * 104 + d] = acc;
  }
  __syncthreads();

  // P9: joint = [self(6), wf(100)]
  if (tid < NB * 106) {
    int b = tid / 106, i = tid - b * 106;
    joint[b * 112 + i] = (i < 6) ? state[(b0 + b) * 260 + i] : wf[b * 104 + (i - 6)];
  }
  __syncthreads();

  // M1: 106->150 relu
  for (int it = tid; it < NB * 150; it += NTHR) {
    int b = it / 150, j = it - b * 150;
    float acc = mb1[j] + mrow_dot<106>(m1, 150, j, &joint[b * 112]);
    v1[b * 152 + j] = relu_f(acc);
  }
  __syncthreads();
  // M2: 150->100 relu
  for (int it = tid; it < NB * 100; it += NTHR) {
    int b = it / 100, j = it - b * 100;
    float acc = mb2[j] + mrow_dot<150>(m2, 100, j, &v1[b * 152]);
    v2[b * 104 + j] = relu_f(acc);
  }
  __syncthreads();
  // M3: 100->100 relu
  for (int it = tid; it < NB * 100; it += NTHR) {
    int b = it / 100, j = it - b * 100;
    float acc = mb3[j] + mrow_dot<100>(m3, 100, j, &v2[b * 104]);
    v3[b * 104 + j] = relu_f(acc);
  }
  __syncthreads();
  // M4: 100->1
  if (tid < NB * 100) {
    int b = tid / 100, d = tid - b * 100;
    psum[tid] = v3[b * 104 + d] * m4[d];
  }
  __syncthreads();
  if (tid < NB) {
    float s = 0.f;
    for (int d = 0; d < 100; ++d) s += psum[tid * 100 + d];
    out[b0 + tid] = s + mb4[0];
  }
}

extern "C" void kernel_launch(void* const* d_in, const int* in_sizes, int n_in,
                              void* d_out, int out_size, void* d_ws, size_t ws_size,
                              hipStream_t stream) {
  const float* state = (const float*)d_in[0];
  const float* w1 = (const float*)d_in[1];
  const float* b1 = (const float*)d_in[2];
  const float* w2 = (const float*)d_in[3];
  const float* b2 = (const float*)d_in[4];
  const float* w3 = (const float*)d_in[5];
  const float* b3 = (const float*)d_in[6];
  const float* a1 = (const float*)d_in[7];
  const float* ab1 = (const float*)d_in[8];
  const float* a2 = (const float*)d_in[9];
  const float* ab2 = (const float*)d_in[10];
  const float* a3 = (const float*)d_in[11];
  const float* ab3 = (const float*)d_in[12];
  const float* m1 = (const float*)d_in[13];
  const float* mb1 = (const float*)d_in[14];
  const float* m2 = (const float*)d_in[15];
  const float* mb2 = (const float*)d_in[16];
  const float* m3 = (const float*)d_in[17];
  const float* mb3 = (const float*)d_in[18];
  const float* m4 = (const float*)d_in[19];
  const float* mb4 = (const float*)d_in[20];
  float* out = (float*)d_out;

  const int B = in_sizes[0] / 260;  // 16384
  dim3 grid(B / NB), block(NTHR);
  value_net_kernel<<<grid, block, 0, stream>>>(
      state, w1, b1, w2, b2, w3, b3, a1, ab1, a2, ab2, a3, ab3,
      m1, mb1, m2, mb2, m3, mb3, m4, mb4, out);
}

// Round 2
// 445.621 us; speedup vs baseline: 1.6036x; 1.6036x over previous
//
#include <hip/hip_runtime.h>
#include <math.h>

#define NTHR 256
#define NB 2              // batches per WG
#define NROWSR (NB * 20)  // 40 real rows
#define MT 3              // M tiles (48 padded rows)

using bf8 = __attribute__((ext_vector_type(8))) short;
using f4  = __attribute__((ext_vector_type(4))) float;

// LDS pool offsets (bytes, all mult of 16). Planar hi/lo bf16 buffers:
// layout [plane][48 rows][PK bf16]; plane stride = 48*PK*2 bytes.
#define XS_OFF 0
#define XS_PK 40
#define H1_OFF 7680
#define H1_PK 168
#define H2_OFF 39936
#define H2_PK 136
#define FEAT_OFF 0       // aliases XS+H1 (dead by P3)
#define FEAT_PK 136
#define S1_OFF 26112     // aliases H1 tail + H2 head (dead by P5)
#define S1_PK 136
#define S2_OFF 52224     // fp32 [40][104]
#define POOL_BYTES 68864

// ws fragment-block bases (1 KB blocks; block = 64 lanes x 16 B)
#define L1B 0
#define L2B 20
#define L3B 90
#define A1B 146
#define A2B 202
#define WS_BLOCKS 258

__device__ __forceinline__ float relu_f(float v) { return fmaxf(v, 0.f); }
__device__ __forceinline__ float us2f(ushort u) {
  return __builtin_bit_cast(float, (uint)u << 16);
}

// ---------------- prep kernel: pack hi/lo bf16 B-fragments ----------------
// Frag layout per (kb, nt, plane): lane l holds col j = nt*16 + (l&15),
// k = kb*32 + (l>>4)*8 + e, e=0..7 -> 16 B contiguous per lane.
__global__ __launch_bounds__(64) void prep_kernel(
    const float* __restrict__ w1, const float* __restrict__ w2,
    const float* __restrict__ w3, const float* __restrict__ a1,
    const float* __restrict__ a2, uint4* __restrict__ ws) {
  const int job = blockIdx.x;
  const int lane = threadIdx.x;
  const float* W;
  int K, C, NT, base, kb, nt;
  if (job < 10)       { W = w1; K = 13;  C = 150; NT = 10; base = L1B; kb = 0; nt = job; }
  else if (job < 45)  { W = w2; K = 150; C = 100; NT = 7;  base = L2B; int i = job - 10;  kb = i / 7; nt = i % 7; }
  else if (job < 73)  { W = w3; K = 100; C = 100; NT = 7;  base = L3B; int i = job - 45;  kb = i / 7; nt = i % 7; }
  else if (job < 101) { W = a1; K = 100; C = 100; NT = 7;  base = A1B; int i = job - 73;  kb = i / 7; nt = i % 7; }
  else                { W = a2; K = 100; C = 100; NT = 7;  base = A2B; int i = job - 101; kb = i / 7; nt = i % 7; }
  const int r = lane & 15, g = lane >> 4;
  const int j = nt * 16 + r;
  uint hi[8], lo[8];
  for (int e = 0; e < 8; ++e) {
    int k = kb * 32 + g * 8 + e;
    float v = (k < K && j < C) ? W[k * C + j] : 0.f;
    uint bits = __builtin_bit_cast(uint, v);
    hi[e] = bits >> 16;
    float hf = __builtin_bit_cast(float, bits & 0xffff0000u);
    float lf = v - hf;
    lo[e] = __builtin_bit_cast(uint, lf) >> 16;
  }
  uint4 vh = { hi[0] | (hi[1] << 16), hi[2] | (hi[3] << 16),
               hi[4] | (hi[5] << 16), hi[6] | (hi[7] << 16) };
  uint4 vl = { lo[0] | (lo[1] << 16), lo[2] | (lo[3] << 16),
               lo[4] | (lo[5] << 16), lo[6] | (lo[7] << 16) };
  ws[(size_t)(base + (kb * NT + nt) * 2 + 0) * 64 + lane] = vh;
  ws[(size_t)(base + (kb * NT + nt) * 2 + 1) * 64 + lane] = vl;
}

// ---------------- MFMA dense layer ----------------
// MODE: 0 = relu planar-out, 1 = linear planar-out (feat),
//       2 = relu + gpart planar-out (A1), 3 = relu fp32-out (A2 -> s2)
template <int KB, int NT, int C, int MODE>
__device__ __forceinline__ void mfma_layer(
    char* pool, int inOff, int PKin, int outOff, int PKout,
    const bf8* __restrict__ wsB, const float* __restrict__ bias,
    const float* __restrict__ gpartL, float* __restrict__ s2L,
    int lane, int wid) {
  constexpr int NTP = (NT + 1) / 2;
  const int r = lane & 15, g = lane >> 4;
  const char* Ain = pool + inOff;
  const int pstrIn = 48 * PKin * 2;
  for (int ntp = wid; ntp < NTP; ntp += 4) {
    const int nt0 = 2 * ntp;
    const bool two = (nt0 + 1 < NT);
    bf8 bh0[KB], bl0[KB], bh1[KB], bl1[KB];
#pragma unroll
    for (int kb = 0; kb < KB; ++kb) {
      bh0[kb] = wsB[((kb * NT + nt0) * 2 + 0) * 64 + lane];
      bl0[kb] = wsB[((kb * NT + nt0) * 2 + 1) * 64 + lane];
      if (two) {
        bh1[kb] = wsB[((kb * NT + nt0 + 1) * 2 + 0) * 64 + lane];
        bl1[kb] = wsB[((kb * NT + nt0 + 1) * 2 + 1) * 64 + lane];
      }
    }
    for (int mt = 0; mt < MT; ++mt) {
      f4 acc0 = {0.f, 0.f, 0.f, 0.f}, acc1 = {0.f, 0.f, 0.f, 0.f};
      const char* aHi = Ain + (mt * 16 + r) * (PKin * 2) + g * 16;
      const char* aLo = aHi + pstrIn;
#pragma unroll
      for (int kb = 0; kb < KB; ++kb) {
        bf8 ah = *(const bf8*)(aHi + kb * 64);
        bf8 al = *(const bf8*)(aLo + kb * 64);
        acc0 = __builtin_amdgcn_mfma_f32_16x16x32_bf16(ah, bh0[kb], acc0, 0, 0, 0);
        if (two) acc1 = __builtin_amdgcn_mfma_f32_16x16x32_bf16(ah, bh1[kb], acc1, 0, 0, 0);
        acc0 = __builtin_amdgcn_mfma_f32_16x16x32_bf16(al, bh0[kb], acc0, 0, 0, 0);
        if (two) acc1 = __builtin_amdgcn_mfma_f32_16x16x32_bf16(al, bh1[kb], acc1, 0, 0, 0);
        acc0 = __builtin_amdgcn_mfma_f32_16x16x32_bf16(ah, bl0[kb], acc0, 0, 0, 0);
        if (two) acc1 = __builtin_amdgcn_mfma_f32_16x16x32_bf16(ah, bl1[kb], acc1, 0, 0, 0);
      }
#pragma unroll
      for (int t = 0; t < 2; ++t) {
        if (t && !two) break;
        const int nt = nt0 + t;
        const f4 acc = t ? acc1 : acc0;
        const int col = nt * 16 + r;
        const int rbase = mt * 16 + g * 4;
        float bcol = 0.f, gp = 0.f;
        if (col < C) {
          bcol = bias[col];
          if constexpr (MODE == 2) {
            int rb = rbase / 20;
            if (rb < NB) gp = gpartL[rb * 104 + col];
          }
        }
#pragma unroll
        for (int q = 0; q < 4; ++q) {
          const int orow = rbase + q;
          float v = 0.f;
          if (orow < NROWSR && col < C) {
            v = acc[q] + bcol;
            if constexpr (MODE == 2) v += gp;
            if constexpr (MODE != 1) v = fmaxf(v, 0.f);
          }
          if constexpr (MODE == 3) {
            if (orow < NROWSR && col < C) s2L[orow * 104 + col] = v;
          } else {
            uint bits = __builtin_bit_cast(uint, v);
            float hf = __builtin_bit_cast(float, bits & 0xffff0000u);
            float lf = v - hf;
            ushort* oHi = (ushort*)(pool + outOff) + orow * PKout + col;
            oHi[0] = (ushort)(bits >> 16);
            oHi[48 * PKout] = (ushort)(__builtin_bit_cast(uint, lf) >> 16);
          }
        }
      }
    }
  }
}

// zero cols [112,128) of a PK=136 planar buffer (MFMA K-read pad)
__device__ __forceinline__ void zero_tail136(char* pool, int off, int tid) {
  if (tid < 96) {
    char* b = pool + off + (tid / 48) * (48 * 272) + (tid % 48) * 272 + 224;
    ((uint4*)b)[0] = uint4{0, 0, 0, 0};
    ((uint4*)b)[1] = uint4{0, 0, 0, 0};
  }
}

template <int K>
__device__ __forceinline__ float mrow_dot(const float* __restrict__ Wt, int C, int j,
                                          const float* xin) {
  float acc = 0.f;
  int k0 = 0;
  for (; k0 + 4 <= K; k0 += 4) {
    float4 xv = *reinterpret_cast<const float4*>(&xin[k0]);
    acc += xv.x * Wt[(k0 + 0) * C + j];
    acc += xv.y * Wt[(k0 + 1) * C + j];
    acc += xv.z * Wt[(k0 + 2) * C + j];
    acc += xv.w * Wt[(k0 + 3) * C + j];
  }
  for (; k0 < K; ++k0) acc += xin[k0] * Wt[k0 * C + j];
  return acc;
}

__global__ __launch_bounds__(NTHR, 2) void value_net_kernel(
    const float* __restrict__ state,
    const float* __restrict__ b1, const float* __restrict__ b2,
    const float* __restrict__ b3,
    const float* __restrict__ a1, const float* __restrict__ ab1,
    const float* __restrict__ ab2,
    const float* __restrict__ a3, const float* __restrict__ ab3,
    const float* __restrict__ m1, const float* __restrict__ mb1,
    const float* __restrict__ m2, const float* __restrict__ mb2,
    const float* __restrict__ m3, const float* __restrict__ mb3,
    const float* __restrict__ m4, const float* __restrict__ mb4,
    const uint4* __restrict__ ws, float* __restrict__ out) {
  __shared__ char pool[POOL_BYTES];
  __shared__ float gsL[2 * 104], gpartL[2 * 104], sceL[64], swL[64],
      wfL[2 * 104], jointL[2 * 112], v1L[2 * 152], v2L[2 * 104],
      v3L[2 * 104], psumL[200];

  const int tid = threadIdx.x;
  const int lane = tid & 63, wid = tid >> 6;
  const int b0 = blockIdx.x * NB;
  const bf8* wsb = (const bf8*)ws;
  float* s2L = (float*)(pool + S2_OFF);

  // P0: stage state -> xs planar hi/lo (rows 40..47 and cols 13..39 zero)
  for (int i = tid; i < 48 * XS_PK; i += NTHR) {
    int row = i / XS_PK, k = i - row * XS_PK;
    float v = 0.f;
    if (row < NROWSR && k < 13) v = state[(b0 * 20 + row) * 13 + k];
    uint bits = __builtin_bit_cast(uint, v);
    float hf = __builtin_bit_cast(float, bits & 0xffff0000u);
    float lf = v - hf;
    ushort* p = (ushort*)(pool + XS_OFF) + row * XS_PK + k;
    p[0] = (ushort)(bits >> 16);
    p[48 * XS_PK] = (ushort)(__builtin_bit_cast(uint, lf) >> 16);
  }
  __syncthreads();

  // P1: L1 13->150 relu
  mfma_layer<1, 10, 150, 0>(pool, XS_OFF, XS_PK, H1_OFF, H1_PK,
                            wsb + L1B * 64, b1, nullptr, nullptr, lane, wid);
  __syncthreads();

  // P2: L2 150->100 relu
  zero_tail136(pool, H2_OFF, tid);
  mfma_layer<5, 7, 100, 0>(pool, H1_OFF, H1_PK, H2_OFF, H2_PK,
                           wsb + L2B * 64, b2, nullptr, nullptr, lane, wid);
  __syncthreads();

  // P3: L3 100->100 linear -> feat
  zero_tail136(pool, FEAT_OFF, tid);
  mfma_layer<4, 7, 100, 1>(pool, H2_OFF, H2_PK, FEAT_OFF, FEAT_PK,
                           wsb + L3B * 64, b3, nullptr, nullptr, lane, wid);
  __syncthreads();

  // P4: gs = mean over n
  {
    const ushort* fh = (const ushort*)(pool + FEAT_OFF);
    const ushort* fl = fh + 48 * FEAT_PK;
    if (tid < NB * 100) {
      int b = tid / 100, d = tid - b * 100;
      float s = 0.f;
      for (int n = 0; n < 20; ++n) {
        int rw = b * 20 + n;
        s += us2f(fh[rw * FEAT_PK + d]) + us2f(fl[rw * FEAT_PK + d]);
      }
      gsL[b * 104 + d] = s * 0.05f;
    }
  }
  __syncthreads();

  // P4b: gpart = gs @ a1[100:200]
  if (tid < NB * 100) {
    int b = tid / 100, j = tid - b * 100;
    float acc = 0.f;
    for (int k = 0; k < 100; ++k) acc += gsL[b * 104 + k] * a1[(100 + k) * 100 + j];
    gpartL[b * 104 + j] = acc;
  }
  __syncthreads();

  // P5: A1 (feat half) + gpart, relu -> s1
  zero_tail136(pool, S1_OFF, tid);
  mfma_layer<4, 7, 100, 2>(pool, FEAT_OFF, FEAT_PK, S1_OFF, S1_PK,
                           wsb + A1B * 64, ab1, gpartL, nullptr, lane, wid);
  __syncthreads();

  // P6: A2 relu -> s2 (fp32)
  mfma_layer<4, 7, 100, 3>(pool, S1_OFF, S1_PK, 0, 0,
                           wsb + A2B * 64, ab2, nullptr, s2L, lane, wid);
  __syncthreads();

  // P7: A3 100->1 relu -> scores
  if (tid < NROWSR) {
    float acc = ab3[0];
    const float* srow = s2L + tid * 104;
    for (int k = 0; k < 100; k += 4) {
      float4 x = *(const float4*)(srow + k);
      acc += x.x * a3[k] + x.y * a3[k + 1] + x.z * a3[k + 2] + x.w * a3[k + 3];
    }
    sceL[(tid / 20) * 32 + (tid % 20)] = relu_f(acc);
  }
  __syncthreads();

  // P7b: softmax over n
  if (tid < NROWSR) {
    int b = tid / 20, n = tid - b * 20;
    float m = -1e30f;
    for (int i = 0; i < 20; ++i) m = fmaxf(m, sceL[b * 32 + i]);
    float sum = 0.f, mine = 0.f;
    for (int i = 0; i < 20; ++i) {
      float e = __expf(sceL[b * 32 + i] - m);
      sum += e;
      if (i == n) mine = e;
    }
    swL[b * 32 + n] = mine / sum;
  }
  __syncthreads();

  // P8: weighted feature
  {
    const ushort* fh = (const ushort*)(pool + FEAT_OFF);
    const ushort* fl = fh + 48 * FEAT_PK;
    if (tid < NB * 100) {
      int b = tid / 100, d = tid - b * 100;
      float acc = 0.f;
      for (int n = 0; n < 20; ++n) {
        int rw = b * 20 + n;
        acc += swL[b * 32 + n] * (us2f(fh[rw * FEAT_PK + d]) + us2f(fl[rw * FEAT_PK + d]));
      }
      wfL[b * 104 + d] = acc;
    }
  }
  __syncthreads();

  // P9: joint = [self(6), wf(100)]
  if (tid < NB * 106) {
    int b = tid / 106, i = tid - b * 106;
    jointL[b * 112 + i] = (i < 6) ? state[(b0 + b) * 260 + i] : wfL[b * 104 + (i - 6)];
  }
  __syncthreads();

  // M1: 106->150 relu
  for (int it = tid; it < NB * 150; it += NTHR) {
    int b = it / 150, j = it - b * 150;
    float acc = mb1[j] + mrow_dot<106>(m1, 150, j, &jointL[b * 112]);
    v1L[b * 152 + j] = relu_f(acc);
  }
  __syncthreads();
  // M2: 150->100 relu
  for (int it = tid; it < NB * 100; it += NTHR) {
    int b = it / 100, j = it - b * 100;
    float acc = mb2[j] + mrow_dot<150>(m2, 100, j, &v1L[b * 152]);
    v2L[b * 104 + j] = relu_f(acc);
  }
  __syncthreads();
  // M3: 100->100 relu
  for (int it = tid; it < NB * 100; it += NTHR) {
    int b = it / 100, j = it - b * 100;
    float acc = mb3[j] + mrow_dot<100>(m3, 100, j, &v2L[b * 104]);
    v3L[b * 104 + j] = relu_f(acc);
  }
  __syncthreads();
  // M4: 100->1
  if (tid < NB * 100) {
    int b = tid / 100, d = tid - b * 100;
    psumL[tid] = v3L[b * 104 + d] * m4[d];
  }
  __syncthreads();
  if (tid < NB) {
    float s = 0.f;
    for (int d = 0; d < 100; ++d) s += psumL[tid * 100 + d];
    out[b0 + tid] = s + mb4[0];
  }
}

extern "C" void kernel_launch(void* const* d_in, const int* in_sizes, int n_in,
                              void* d_out, int out_size, void* d_ws, size_t ws_size,
                              hipStream_t stream) {
  const float* state = (const float*)d_in[0];
  const float* w1 = (const float*)d_in[1];
  const float* b1 = (const float*)d_in[2];
  const float* w2 = (const float*)d_in[3];
  const float* b2 = (const float*)d_in[4];
  const float* w3 = (const float*)d_in[5];
  const float* b3 = (const float*)d_in[6];
  const float* a1 = (const float*)d_in[7];
  const float* ab1 = (const float*)d_in[8];
  const float* a2 = (const float*)d_in[9];
  const float* ab2 = (const float*)d_in[10];
  const float* a3 = (const float*)d_in[11];
  const float* ab3 = (const float*)d_in[12];
  const float* m1 = (const float*)d_in[13];
  const float* mb1 = (const float*)d_in[14];
  const float* m2 = (const float*)d_in[15];
  const float* mb2 = (const float*)d_in[16];
  const float* m3 = (const float*)d_in[17];
  const float* mb3 = (const float*)d_in[18];
  const float* m4 = (const float*)d_in[19];
  const float* mb4 = (const float*)d_in[20];
  float* out = (float*)d_out;
  uint4* ws = (uint4*)d_ws;

  // pack weight fragments (258 KB in d_ws)
  prep_kernel<<<129, 64, 0, stream>>>(w1, w2, w3, a1, a2, ws);

  const int B = in_sizes[0] / 260;  // 16384
  dim3 grid(B / NB), block(NTHR);
  value_net_kernel<<<grid, block, 0, stream>>>(
      state, b1, b2, b3, a1, ab1, ab2, a3, ab3,
      m1, mb1, m2, mb2, m3, mb3, m4, mb4, (const uint4*)ws, out);
}

// Round 3
// 348.598 us; speedup vs baseline: 2.0500x; 1.2783x over previous
//
#include <hip/hip_runtime.h>
#include <math.h>

#define NTHR 512
#define NB 2              // batches per WG (kernel1)
#define NROWSR (NB * 20)  // 40 real rows
#define MTK1 3            // M tiles kernel1 (48 padded rows)

using bf8 = __attribute__((ext_vector_type(8))) short;
using f4  = __attribute__((ext_vector_type(4))) float;

// kernel1 LDS pool offsets (bytes). Planar hi/lo bf16: [plane][48][PK].
#define XS_OFF 0
#define XS_PK 40
#define H1_OFF 7680
#define H1_PK 168
#define H2_OFF 39936
#define H2_PK 136
#define FEAT_OFF 0       // aliases XS+H1 (dead by P3)
#define FEAT_PK 136
#define S1_OFF 26112     // aliases H1 tail + H2 head (dead by P5)
#define S1_PK 136
#define S2_OFF 52224     // fp32 [40][104]
#define POOL_BYTES 68864

// ws fragment bases (1KB blocks; each (kb,nt) pair = 2 blocks hi+lo)
#define L1B 0
#define L2B 20
#define L3B 90
#define A1B 146
#define A2B 202
#define M1B 258
#define M2B 338
#define M3B 408
#define WS_BLOCKS 464
#define JOINT_F 118784   // float offset of joint[16384][106] in ws

// kernel2
#define K2ROWS 64
#define K2THR 256
#define K2_JT_OFF 0      // 64*136*2*2 = 34816
#define K2_V1_OFF 34816  // 64*168*2*2 = 43008 -> end 77824
#define K2_POOL 77824

__device__ __forceinline__ float relu_f(float v) { return fmaxf(v, 0.f); }
__device__ __forceinline__ float us2f(ushort u) {
  return __builtin_bit_cast(float, (uint)u << 16);
}
__device__ __forceinline__ void split_store(float v, ushort* p, int pstride) {
  uint bits = __builtin_bit_cast(uint, v);
  float hf = __builtin_bit_cast(float, bits & 0xffff0000u);
  float lf = v - hf;
  p[0] = (ushort)(bits >> 16);
  p[pstride] = (ushort)(__builtin_bit_cast(uint, lf) >> 16);
}

// ---------------- prep: pack hi/lo bf16 B-fragments ----------------
__global__ __launch_bounds__(64) void prep_kernel(
    const float* __restrict__ w1, const float* __restrict__ w2,
    const float* __restrict__ w3, const float* __restrict__ a1,
    const float* __restrict__ a2, const float* __restrict__ m1,
    const float* __restrict__ m2, const float* __restrict__ m3,
    uint4* __restrict__ ws) {
  const int job = blockIdx.x;
  const int lane = threadIdx.x;
  const float* W;
  int K, C, NT, base, kb, nt, i;
  if (job < 10)       { W = w1; K = 13;  C = 150; NT = 10; base = L1B; kb = 0; nt = job; }
  else if (job < 45)  { W = w2; K = 150; C = 100; NT = 7;  base = L2B; i = job - 10;  kb = i / 7;  nt = i % 7; }
  else if (job < 73)  { W = w3; K = 100; C = 100; NT = 7;  base = L3B; i = job - 45;  kb = i / 7;  nt = i % 7; }
  else if (job < 101) { W = a1; K = 100; C = 100; NT = 7;  base = A1B; i = job - 73;  kb = i / 7;  nt = i % 7; }
  else if (job < 129) { W = a2; K = 100; C = 100; NT = 7;  base = A2B; i = job - 101; kb = i / 7;  nt = i % 7; }
  else if (job < 169) { W = m1; K = 106; C = 150; NT = 10; base = M1B; i = job - 129; kb = i / 10; nt = i % 10; }
  else if (job < 204) { W = m2; K = 150; C = 100; NT = 7;  base = M2B; i = job - 169; kb = i / 7;  nt = i % 7; }
  else                { W = m3; K = 100; C = 100; NT = 7;  base = M3B; i = job - 204; kb = i / 7;  nt = i % 7; }
  const int r = lane & 15, g = lane >> 4;
  const int j = nt * 16 + r;
  uint hi[8], lo[8];
  for (int e = 0; e < 8; ++e) {
    int k = kb * 32 + g * 8 + e;
    float v = (k < K && j < C) ? W[k * C + j] : 0.f;
    uint bits = __builtin_bit_cast(uint, v);
    hi[e] = bits >> 16;
    float hf = __builtin_bit_cast(float, bits & 0xffff0000u);
    float lf = v - hf;
    lo[e] = __builtin_bit_cast(uint, lf) >> 16;
  }
  uint4 vh = { hi[0] | (hi[1] << 16), hi[2] | (hi[3] << 16),
               hi[4] | (hi[5] << 16), hi[6] | (hi[7] << 16) };
  uint4 vl = { lo[0] | (lo[1] << 16), lo[2] | (lo[3] << 16),
               lo[4] | (lo[5] << 16), lo[6] | (lo[7] << 16) };
  ws[(size_t)(base + (kb * NT + nt) * 2 + 0) * 64 + lane] = vh;
  ws[(size_t)(base + (kb * NT + nt) * 2 + 1) * 64 + lane] = vl;
}

// ---------------- MFMA dense layer ----------------
// MODE: 0 relu planar-out, 1 linear planar-out, 2 relu+gpart planar-out,
//       3 relu fp32-out (stride 104)
template <int KB, int NT, int C, int MODE, int MTL, int ROWS, int RVALID, bool W8>
__device__ __forceinline__ void mfma_layer(
    char* pool, int inOff, int PKin, int outOff, int PKout,
    const bf8* __restrict__ wsB, const float* __restrict__ bias,
    const float* gpartL, float* s2L, int lane, int wid) {
  constexpr int NTP = (NT + 1) / 2;
  const int r = lane & 15, g = lane >> 4;
  const char* Ain = pool + inOff;
  const int pstrIn = ROWS * PKin * 2;
  int wlo, mtb, mte;
  if constexpr (W8) {
    static_assert(MTL == 3, "W8 split assumes 3 M-tiles");
    wlo = wid & 3;
    const int whi = wid >> 2;
    mtb = whi ? 2 : 0;
    mte = whi ? 3 : 2;
  } else {
    wlo = wid; mtb = 0; mte = MTL;
  }
  for (int p = wlo; p < NTP; p += 4) {
    const int nt0 = 2 * p;
    const bool two = (nt0 + 1 < NT);
    bf8 bh0[KB], bl0[KB], bh1[KB], bl1[KB];
#pragma unroll
    for (int kb = 0; kb < KB; ++kb) {
      bh0[kb] = wsB[((kb * NT + nt0) * 2 + 0) * 64 + lane];
      bl0[kb] = wsB[((kb * NT + nt0) * 2 + 1) * 64 + lane];
      if (two) {
        bh1[kb] = wsB[((kb * NT + nt0 + 1) * 2 + 0) * 64 + lane];
        bl1[kb] = wsB[((kb * NT + nt0 + 1) * 2 + 1) * 64 + lane];
      }
    }
    for (int mt = mtb; mt < mte; ++mt) {
      f4 acc0 = {0.f, 0.f, 0.f, 0.f}, acc1 = {0.f, 0.f, 0.f, 0.f};
      const char* aHi = Ain + (mt * 16 + r) * (PKin * 2) + g * 16;
      const char* aLo = aHi + pstrIn;
#pragma unroll
      for (int kb = 0; kb < KB; ++kb) {
        bf8 ah = *(const bf8*)(aHi + kb * 64);
        bf8 al = *(const bf8*)(aLo + kb * 64);
        acc0 = __builtin_amdgcn_mfma_f32_16x16x32_bf16(ah, bh0[kb], acc0, 0, 0, 0);
        if (two) acc1 = __builtin_amdgcn_mfma_f32_16x16x32_bf16(ah, bh1[kb], acc1, 0, 0, 0);
        acc0 = __builtin_amdgcn_mfma_f32_16x16x32_bf16(al, bh0[kb], acc0, 0, 0, 0);
        if (two) acc1 = __builtin_amdgcn_mfma_f32_16x16x32_bf16(al, bh1[kb], acc1, 0, 0, 0);
        acc0 = __builtin_amdgcn_mfma_f32_16x16x32_bf16(ah, bl0[kb], acc0, 0, 0, 0);
        if (two) acc1 = __builtin_amdgcn_mfma_f32_16x16x32_bf16(ah, bl1[kb], acc1, 0, 0, 0);
      }
#pragma unroll
      for (int t = 0; t < 2; ++t) {
        if (t && !two) break;
        const int nt = nt0 + t;
        const f4 acc = t ? acc1 : acc0;
        const int col = nt * 16 + r;
        const int rbase = mt * 16 + g * 4;
        float bcol = 0.f, gp = 0.f;
        if (col < C) {
          bcol = bias[col];
          if constexpr (MODE == 2) {
            int rb = rbase / 20;
            if (rb < NB) gp = gpartL[rb * 104 + col];
          }
        }
#pragma unroll
        for (int q = 0; q < 4; ++q) {
          const int orow = rbase + q;
          float v = 0.f;
          if (orow < RVALID && col < C) {
            v = acc[q] + bcol;
            if constexpr (MODE == 2) v += gp;
            if constexpr (MODE != 1) v = fmaxf(v, 0.f);
          }
          if constexpr (MODE == 3) {
            if (orow < RVALID && col < C) s2L[orow * 104 + col] = v;
          } else {
            ushort* oHi = (ushort*)(pool + outOff) + orow * PKout + col;
            split_store(v, oHi, ROWS * PKout);
          }
        }
      }
    }
  }
}

// zero cols [100,128) of a PK=136 planar buffer
template <int ROWS>
__device__ __forceinline__ void zero_tail136(char* pool, int off, int tid) {
  if (tid < 2 * ROWS) {
    int row = tid >> 1, pl = tid & 1;
    uint2* z = (uint2*)((ushort*)(pool + off) + pl * ROWS * 136 + row * 136 + 100);
#pragma unroll
    for (int u = 0; u < 7; ++u) z[u] = uint2{0, 0};
  }
}
// zero cols [150,160) of a PK=168 planar buffer
template <int ROWS>
__device__ __forceinline__ void zero_tail168(char* pool, int off, int tid) {
  if (tid < 2 * ROWS) {
    int row = tid >> 1, pl = tid & 1;
    uint* z = (uint*)((ushort*)(pool + off) + pl * ROWS * 168 + row * 168 + 150);
#pragma unroll
    for (int u = 0; u < 5; ++u) z[u] = 0;
  }
}

// ---------------- kernel1: per-group MLP1 + attention -> joint ----------------
__global__ __launch_bounds__(NTHR, 4) void value_net_kernel(
    const float* __restrict__ state,
    const float* __restrict__ b1, const float* __restrict__ b2,
    const float* __restrict__ b3,
    const float* __restrict__ a1, const float* __restrict__ ab1,
    const float* __restrict__ ab2,
    const float* __restrict__ a3, const float* __restrict__ ab3,
    const uint4* __restrict__ ws, float* __restrict__ jointg) {
  __shared__ char pool[POOL_BYTES];
  __shared__ float gsL[2 * 104], gpartL[2 * 104], sceL[64], swL[64], wfL[2 * 104];

  const int tid = threadIdx.x;
  const int lane = tid & 63, wid = tid >> 6;
  const int b0 = blockIdx.x * NB;
  const bf8* wsb = (const bf8*)ws;
  float* s2L = (float*)(pool + S2_OFF);

  // P0: stage state -> xs planar hi/lo; zero H1 pad cols [150,160)
  for (int i = tid; i < 48 * XS_PK; i += NTHR) {
    int row = i / XS_PK, k = i - row * XS_PK;
    float v = 0.f;
    if (row < NROWSR && k < 13) v = state[(b0 * 20 + row) * 13 + k];
    split_store(v, (ushort*)(pool + XS_OFF) + row * XS_PK + k, 48 * XS_PK);
  }
  zero_tail168<48>(pool, H1_OFF, tid);
  __syncthreads();

  // P1: L1 13->150 relu
  mfma_layer<1, 10, 150, 0, MTK1, 48, NROWSR, true>(
      pool, XS_OFF, XS_PK, H1_OFF, H1_PK, wsb + L1B * 64, b1, nullptr, nullptr, lane, wid);
  __syncthreads();

  // P2: L2 150->100 relu
  zero_tail136<48>(pool, H2_OFF, tid);
  mfma_layer<5, 7, 100, 0, MTK1, 48, NROWSR, true>(
      pool, H1_OFF, H1_PK, H2_OFF, H2_PK, wsb + L2B * 64, b2, nullptr, nullptr, lane, wid);
  __syncthreads();

  // P3: L3 100->100 linear -> feat
  zero_tail136<48>(pool, FEAT_OFF, tid);
  mfma_layer<4, 7, 100, 1, MTK1, 48, NROWSR, true>(
      pool, H2_OFF, H2_PK, FEAT_OFF, FEAT_PK, wsb + L3B * 64, b3, nullptr, nullptr, lane, wid);
  __syncthreads();

  // P4: gs = mean over n
  {
    const ushort* fh = (const ushort*)(pool + FEAT_OFF);
    const ushort* fl = fh + 48 * FEAT_PK;
    if (tid < NB * 100) {
      int b = tid / 100, d = tid - b * 100;
      float s = 0.f;
      for (int n = 0; n < 20; ++n) {
        int rw = b * 20 + n;
        s += us2f(fh[rw * FEAT_PK + d]) + us2f(fl[rw * FEAT_PK + d]);
      }
      gsL[b * 104 + d] = s * 0.05f;
    }
  }
  __syncthreads();

  // P4b: gpart = gs @ a1[100:200]
  if (tid < NB * 100) {
    int b = tid / 100, j = tid - b * 100;
    float acc = 0.f;
    for (int k = 0; k < 100; ++k) acc += gsL[b * 104 + k] * a1[(100 + k) * 100 + j];
    gpartL[b * 104 + j] = acc;
  }
  __syncthreads();

  // P5: A1 (feat half) + gpart, relu -> s1
  zero_tail136<48>(pool, S1_OFF, tid);
  mfma_layer<4, 7, 100, 2, MTK1, 48, NROWSR, true>(
      pool, FEAT_OFF, FEAT_PK, S1_OFF, S1_PK, wsb + A1B * 64, ab1, gpartL, nullptr, lane, wid);
  __syncthreads();

  // P6: A2 relu -> s2 (fp32)
  mfma_layer<4, 7, 100, 3, MTK1, 48, NROWSR, true>(
      pool, S1_OFF, S1_PK, 0, 0, wsb + A2B * 64, ab2, nullptr, s2L, lane, wid);
  __syncthreads();

  // P7: A3 100->1 relu (4-way split + shfl reduce)
  if (tid < 4 * NROWSR) {
    int row = tid >> 2, seg = tid & 3;
    const float* srow = s2L + row * 104;
    float acc = 0.f;
    for (int k = seg; k < 100; k += 4) acc += srow[k] * a3[k];
    acc += __shfl_xor(acc, 1);
    acc += __shfl_xor(acc, 2);
    if (seg == 0) sceL[(row / 20) * 32 + (row % 20)] = relu_f(acc + ab3[0]);
  }
  __syncthreads();

  // P7b: softmax over n
  if (tid < NROWSR) {
    int b = tid / 20, n = tid - b * 20;
    float m = -1e30f;
    for (int i = 0; i < 20; ++i) m = fmaxf(m, sceL[b * 32 + i]);
    float sum = 0.f, mine = 0.f;
    for (int i = 0; i < 20; ++i) {
      float e = __expf(sceL[b * 32 + i] - m);
      sum += e;
      if (i == n) mine = e;
    }
    swL[b * 32 + n] = mine / sum;
  }
  __syncthreads();

  // P8: weighted feature
  {
    const ushort* fh = (const ushort*)(pool + FEAT_OFF);
    const ushort* fl = fh + 48 * FEAT_PK;
    if (tid < NB * 100) {
      int b = tid / 100, d = tid - b * 100;
      float acc = 0.f;
      for (int n = 0; n < 20; ++n) {
        int rw = b * 20 + n;
        acc += swL[b * 32 + n] * (us2f(fh[rw * FEAT_PK + d]) + us2f(fl[rw * FEAT_PK + d]));
      }
      wfL[b * 104 + d] = acc;
    }
  }
  __syncthreads();

  // P9: joint = [self(6), wf(100)] -> global ws
  if (tid < NB * 106) {
    int b = tid / 106, i = tid - b * 106;
    jointg[(size_t)(b0 + b) * 106 + i] =
        (i < 6) ? state[(b0 + b) * 260 + i] : wfL[b * 104 + (i - 6)];
  }
}

// ---------------- kernel2: M-MLP GEMM over 16384 rows ----------------
__global__ __launch_bounds__(K2THR) void mlp2_kernel(
    const float* __restrict__ jointg,
    const float* __restrict__ mb1, const float* __restrict__ mb2,
    const float* __restrict__ mb3,
    const float* __restrict__ m4, const float* __restrict__ mb4,
    const uint4* __restrict__ ws, float* __restrict__ out) {
  __shared__ char pool[K2_POOL];
  __shared__ float m4L[100];
  const int tid = threadIdx.x, lane = tid & 63, wid = tid >> 6;
  const size_t r0 = (size_t)blockIdx.x * K2ROWS;
  const bf8* wsb = (const bf8*)ws;

  // stage joint -> planar hi/lo (PK=136, cols 106..135 zero); m4 -> LDS
  for (int i = tid; i < K2ROWS * 136; i += K2THR) {
    int row = i / 136, k = i - row * 136;
    float v = (k < 106) ? jointg[(r0 + row) * 106 + k] : 0.f;
    split_store(v, (ushort*)(pool + K2_JT_OFF) + row * 136 + k, K2ROWS * 136);
  }
  if (tid < 100) m4L[tid] = m4[tid];
  zero_tail168<K2ROWS>(pool, K2_V1_OFF, tid);
  __syncthreads();

  // M1: 106->150 relu (joint PK136 -> v1 PK168)
  mfma_layer<4, 10, 150, 0, 4, K2ROWS, K2ROWS, false>(
      pool, K2_JT_OFF, 136, K2_V1_OFF, 168, wsb + M1B * 64, mb1, nullptr, nullptr, lane, wid);
  __syncthreads();

  // M2: 150->100 relu (v1 -> v2 @0, PK136)
  zero_tail136<K2ROWS>(pool, 0, tid);
  mfma_layer<5, 7, 100, 0, 4, K2ROWS, K2ROWS, false>(
      pool, K2_V1_OFF, 168, 0, 136, wsb + M2B * 64, mb2, nullptr, nullptr, lane, wid);
  __syncthreads();

  // M3: 100->100 relu (v2 -> v3 @34816, PK136)
  mfma_layer<4, 7, 100, 0, 4, K2ROWS, K2ROWS, false>(
      pool, 0, 136, K2_V1_OFF, 136, wsb + M3B * 64, mb3, nullptr, nullptr, lane, wid);
  __syncthreads();

  // M4: 100->1
  {
    int row = tid >> 2, seg = tid & 3;
    const ushort* vh = (const ushort*)(pool + K2_V1_OFF);
    const ushort* vl = vh + K2ROWS * 136;
    float s = 0.f;
    for (int k = seg; k < 100; k += 4)
      s += (us2f(vh[row * 136 + k]) + us2f(vl[row * 136 + k])) * m4L[k];
    s += __shfl_xor(s, 1);
    s += __shfl_xor(s, 2);
    if (seg == 0) out[r0 + row] = s + mb4[0];
  }
}

extern "C" void kernel_launch(void* const* d_in, const int* in_sizes, int n_in,
                              void* d_out, int out_size, void* d_ws, size_t ws_size,
                              hipStream_t stream) {
  const float* state = (const float*)d_in[0];
  const float* w1 = (const float*)d_in[1];
  const float* b1 = (const float*)d_in[2];
  const float* w2 = (const float*)d_in[3];
  const float* b2 = (const float*)d_in[4];
  const float* w3 = (const float*)d_in[5];
  const float* b3 = (const float*)d_in[6];
  const float* a1 = (const float*)d_in[7];
  const float* ab1 = (const float*)d_in[8];
  const float* a2 = (const float*)d_in[9];
  const float* ab2 = (const float*)d_in[10];
  const float* a3 = (const float*)d_in[11];
  const float* ab3 = (const float*)d_in[12];
  const float* m1 = (const float*)d_in[13];
  const float* mb1 = (const float*)d_in[14];
  const float* m2 = (const float*)d_in[15];
  const float* mb2 = (const float*)d_in[16];
  const float* m3 = (const float*)d_in[17];
  const float* mb3 = (const float*)d_in[18];
  const float* m4 = (const float*)d_in[19];
  const float* mb4 = (const float*)d_in[20];
  float* out = (float*)d_out;
  uint4* ws = (uint4*)d_ws;
  float* jointg = (float*)d_ws + JOINT_F;

  prep_kernel<<<232, 64, 0, stream>>>(w1, w2, w3, a1, a2, m1, m2, m3, ws);

  const int B = in_sizes[0] / 260;  // 16384
  value_net_kernel<<<dim3(B / NB), dim3(NTHR), 0, stream>>>(
      state, b1, b2, b3, a1, ab1, ab2, a3, ab3, (const uint4*)ws, jointg);

  mlp2_kernel<<<dim3(B / K2ROWS), dim3(K2THR), 0, stream>>>(
      jointg, mb1, mb2, mb3, m4, mb4, (const uint4*)ws, out);
}